// Round 8
// baseline (49.643 us; speedup 1.0000x reference)
//
#include <hip/hip_runtime.h>

// out = f1>=0 ? f1*winMax9x9(f2pad) : f1*winMin9x9(f2pad)  (separable 9-window)
// WAVE-AUTONOMOUS: one 64-lane wave per plane, LDS as wave-private scratch,
// ZERO s_barrier. Per band (10/10/10/8 rows): V-phase (34 lanes, float2 col
// pairs, van Herk, global->LDS), lgkm-only fence, H-phase (64 lanes,
// ds_read_b128, van Herk, float4 f1 + float4 stores). Waves slip freely ->
// no barrier convoy. LDS 26.9 KB/block -> 6 blocks/CU = 24 waves/CU.

#define HH 38
#define WW 68
#define PLANE (HH * WW)   // 2584
#define ST 84             // LDS row stride (dwords): 4 pad | 68 data | 4 pad | 8 slack
#define NR 10             // max band rows
#define TPB 256           // 4 waves
#define NB 2048           // 8192 planes / 4 waves

#define FENCE() do { asm volatile("s_waitcnt lgkmcnt(0)" ::: "memory"); \
                     __builtin_amdgcn_sched_barrier(0); } while (0)

__device__ __forceinline__ float2 f2max(float2 a, float2 b) {
    return make_float2(fmaxf(a.x, b.x), fmaxf(a.y, b.y));
}
__device__ __forceinline__ float2 f2min(float2 a, float2 b) {
    return make_float2(fminf(a.x, b.x), fminf(a.y, b.y));
}

template <int H0, int NRr, int ILO, int IHI>
__device__ __forceinline__ void do_band(
    const int l, const int base,
    const float* __restrict__ f1, const float* __restrict__ fp,
    float* __restrict__ out,
    float (*__restrict__ bx)[ST], float (*__restrict__ bn)[ST])
{
    // ---- V: vertical 9-window max+min via van Herk, float2 col pairs ----
    if (l < 34) {
        const int c2 = 2 * l;
        float2 v[NRr + 8];
        #pragma unroll
        for (int i = 0; i < NRr + 8; ++i) {
            // row = H0-4+i; valid i range is compile-time [ILO, IHI]
            v[i] = (i >= ILO && i <= IHI)
                 ? *reinterpret_cast<const float2*>(fp + (H0 - 4 + i) * WW + c2)
                 : make_float2(0.0f, 0.0f);
        }
        float2 S[9], P;
        // MAX: S[i]=max(v[i..8]); out[k]=max(v[k..k+8])
        S[8] = v[8];
        #pragma unroll
        for (int i = 7; i >= 0; --i) S[i] = f2max(v[i], S[i + 1]);
        *reinterpret_cast<float2*>(&bx[0][4 + c2]) = S[0];
        P = v[9];
        #pragma unroll
        for (int k = 1; k < NRr; ++k) {
            float2 o = (k <= 8) ? f2max(S[k], P) : P;
            *reinterpret_cast<float2*>(&bx[k][4 + c2]) = o;
            if (9 + k < NRr + 8) P = f2max(P, v[9 + k]);
        }
        // MIN
        S[8] = v[8];
        #pragma unroll
        for (int i = 7; i >= 0; --i) S[i] = f2min(v[i], S[i + 1]);
        *reinterpret_cast<float2*>(&bn[0][4 + c2]) = S[0];
        P = v[9];
        #pragma unroll
        for (int k = 1; k < NRr; ++k) {
            float2 o = (k <= 8) ? f2min(S[k], P) : P;
            *reinterpret_cast<float2*>(&bn[k][4 + c2]) = o;
            if (9 + k < NRr + 8) P = f2min(P, v[9 + k]);
        }
    }

    FENCE();   // wave-private: same-wave LDS visibility needs lgkm drain only

    // ---- H: horizontal 9-window max+min + combine + store ----
    #pragma unroll
    for (int it = 0; it < 2; ++it) {
        const int ji = l + it * 64;
        if (ji < NRr * 9) {
            const int row = ji / 9, seg = ji % 9;
            const int hc0 = (seg < 8) ? seg * 8 : 60;   // seg 8 overlaps (same values)
            float u[16], S[9], wx[8], wn[8], Pp;
            // max: u[i] = phys col hc0+i = real col hc0-4+i
            #pragma unroll
            for (int q = 0; q < 4; ++q)
                *reinterpret_cast<float4*>(&u[q * 4]) =
                    *reinterpret_cast<const float4*>(&bx[row][hc0 + q * 4]);
            S[8] = u[8];
            #pragma unroll
            for (int i = 7; i >= 0; --i) S[i] = fmaxf(u[i], S[i + 1]);
            wx[0] = S[0];
            Pp = u[9];
            #pragma unroll
            for (int k = 1; k < 8; ++k) {               // wx[k] = max(u[k..k+8])
                wx[k] = fmaxf(S[k], Pp);
                if (k < 7) Pp = fmaxf(Pp, u[9 + k]);
            }
            // min
            #pragma unroll
            for (int q = 0; q < 4; ++q)
                *reinterpret_cast<float4*>(&u[q * 4]) =
                    *reinterpret_cast<const float4*>(&bn[row][hc0 + q * 4]);
            S[8] = u[8];
            #pragma unroll
            for (int i = 7; i >= 0; --i) S[i] = fminf(u[i], S[i + 1]);
            wn[0] = S[0];
            Pp = u[9];
            #pragma unroll
            for (int k = 1; k < 8; ++k) {
                wn[k] = fminf(S[k], Pp);
                if (k < 7) Pp = fminf(Pp, u[9 + k]);
            }
            // combine with f1, store 2x float4
            const float* f1r = f1 + base + (H0 + row) * WW + hc0;
            float4 A = *reinterpret_cast<const float4*>(f1r);
            float4 B = *reinterpret_cast<const float4*>(f1r + 4);
            float4 ra, rb;
            ra.x = A.x * (A.x >= 0.0f ? wx[0] : wn[0]);
            ra.y = A.y * (A.y >= 0.0f ? wx[1] : wn[1]);
            ra.z = A.z * (A.z >= 0.0f ? wx[2] : wn[2]);
            ra.w = A.w * (A.w >= 0.0f ? wx[3] : wn[3]);
            rb.x = B.x * (B.x >= 0.0f ? wx[4] : wn[4]);
            rb.y = B.y * (B.y >= 0.0f ? wx[5] : wn[5]);
            rb.z = B.z * (B.z >= 0.0f ? wx[6] : wn[6]);
            rb.w = B.w * (B.w >= 0.0f ? wx[7] : wn[7]);
            float* outp = out + base + (H0 + row) * WW + hc0;
            *reinterpret_cast<float4*>(outp)     = ra;
            *reinterpret_cast<float4*>(outp + 4) = rb;
        }
    }

    FENCE();   // drain H reads before next band's V writes reuse the buffer
}

__global__ __launch_bounds__(TPB) void corr_wave_kernel(
    const float* __restrict__ f1, const float* __restrict__ f2,
    float* __restrict__ out)
{
    __shared__ float lds[TPB / 64][2][NR][ST];   // 26880 B, wave-private slices

    const int t = threadIdx.x;
    const int w = t >> 6, l = t & 63;
    float (*bx)[ST] = lds[w][0];
    float (*bn)[ST] = lds[w][1];

    const int plane = blockIdx.x * (TPB / 64) + w;
    const int base  = plane * PLANE;
    const float* fp = f2 + base;

    // zero pad cols (phys 0..3, 72..75) once; data cols rewritten per band,
    // pads persist. 40 float4 jobs: (r 0..9) x (qty) x (side).
    if (l < 40) {
        int q = l & 1, side = (l >> 1) & 1, r = l >> 2;
        *reinterpret_cast<float4*>(&lds[w][q][r][side ? 72 : 0]) =
            make_float4(0, 0, 0, 0);
    }
    // band 0's FENCE (inside do_band) drains these before first H reads.

    do_band< 0, 10, 4, 17>(l, base, f1, fp, out, bx, bn);   // rows  0..9,  in rows  0..13
    do_band<10, 10, 0, 17>(l, base, f1, fp, out, bx, bn);   // rows 10..19, in rows  6..23
    do_band<20, 10, 0, 17>(l, base, f1, fp, out, bx, bn);   // rows 20..29, in rows 16..33
    do_band<30,  8, 0, 11>(l, base, f1, fp, out, bx, bn);   // rows 30..37, in rows 26..37
}

extern "C" void kernel_launch(void* const* d_in, const int* in_sizes, int n_in,
                              void* d_out, int out_size, void* d_ws, size_t ws_size,
                              hipStream_t stream) {
    const float* f1 = (const float*)d_in[0];
    const float* f2 = (const float*)d_in[1];
    float* out = (float*)d_out;
    corr_wave_kernel<<<dim3(NB), dim3(TPB), 0, stream>>>(f1, f2, out);
}